// Round 1
// baseline (594.159 us; speedup 1.0000x reference)
//
#include <hip/hip_runtime.h>

#define SEQ 600
#define PP 6
#define TOUT 594   // SEQ - PP

// One wave (64 lanes) per row; block = 256 threads = 4 rows.
__global__ __launch_bounds__(256) void ar_fit_kernel(
    const float* __restrict__ x,
    float* __restrict__ coeffs,
    float* __restrict__ x_hat,
    int N)
{
    __shared__ __align__(16) float sxr[4][608];   // row + 8 zero pad
    __shared__ float4 spat[4][3];                 // 12-float repeating coeff pattern

    const int wave = threadIdx.x >> 6;
    const int lane = threadIdx.x & 63;
    const int row  = (blockIdx.x << 2) + wave;
    const bool live = (row < N);   // N=32768 divisible by 4, never false in practice

    // ---- stage row into LDS (coalesced float4) ----
    if (live) {
        const float4* xr = reinterpret_cast<const float4*>(x + (size_t)row * SEQ);
        float4* s4 = reinterpret_cast<float4*>(sxr[wave]);
        for (int i = lane; i < SEQ / 4; i += 64) s4[i] = xr[i];
        if (lane < 8) sxr[wave][SEQ + lane] = 0.0f;
    }
    __syncthreads();

    const float* sx = sxr[wave];
    float w[7];

    if (live) {
        // ---- accumulate S = sum x, Q[d] = sum x[i]*x[i+d], d=0..6 ----
        float S = 0.f;
        float Q[7] = {0.f, 0.f, 0.f, 0.f, 0.f, 0.f, 0.f};
        for (int i = lane; i < SEQ; i += 64) {
            float x0 = sx[i];
            S += x0;
            #pragma unroll
            for (int d = 0; d < 7; ++d) Q[d] += x0 * sx[i + d];
        }
        // butterfly reduce 8 values across the wave (all lanes end with totals)
        #pragma unroll
        for (int m = 1; m < 64; m <<= 1) {
            S += __shfl_xor(S, m, 64);
            #pragma unroll
            for (int d = 0; d < 7; ++d) Q[d] += __shfl_xor(Q[d], m, 64);
        }

        // ---- boundary prefix/suffix sums (uniform broadcast LDS reads) ----
        float pre[8], suf[8];
        pre[0] = 0.f; suf[0] = 0.f;
        #pragma unroll
        for (int c = 1; c < 8; ++c) {
            pre[c] = pre[c - 1] + sx[c - 1];
            suf[c] = suf[c - 1] + sx[SEQ - c];
        }

        // ---- reconstruct normal equations G (7x7) and rhs (7) ----
        // D[t] = (1, x[t+5], x[t+4], ..., x[t]),  y[t] = x[t+6],  t = 0..593
        float M[7][7];
        float rhs[7];
        M[0][0] = (float)TOUT;
        #pragma unroll
        for (int k = 0; k < 6; ++k) {
            // sum over window i in [5-k, 598-k]
            float v = S - pre[5 - k] - suf[k + 1];
            M[0][k + 1] = v; M[k + 1][0] = v;
        }
        #pragma unroll
        for (int k = 0; k < 6; ++k) {
            #pragma unroll
            for (int l = k; l < 6; ++l) {
                const int a = 5 - l, d = l - k;  // C = sum_{i=a}^{a+593} x[i]x[i+d]
                float head = 0.f;
                #pragma unroll
                for (int i = 0; i < a; ++i) head += sx[i] * sx[i + d];
                float tail = 0.f;
                #pragma unroll
                for (int i = a + TOUT; i < SEQ; ++i) tail += sx[i] * sx[i + d];
                float v = Q[d] - head - tail;
                M[k + 1][l + 1] = v; M[l + 1][k + 1] = v;
            }
        }
        rhs[0] = S - pre[6];   // sum of y = x[6..599]
        #pragma unroll
        for (int k = 0; k < 6; ++k) {
            const int a = 5 - k, d = k + 1;
            float head = 0.f;
            #pragma unroll
            for (int i = 0; i < a; ++i) head += sx[i] * sx[i + d];
            float tail = 0.f;
            #pragma unroll
            for (int i = a + TOUT; i < SEQ; ++i) tail += sx[i] * sx[i + d];
            rhs[k + 1] = Q[d] - head - tail;
        }

        // ---- Cholesky solve (G is SPD, cond ~ O(1)); redundant per-lane ----
        #pragma unroll
        for (int j = 0; j < 7; ++j) {
            float s = M[j][j];
            #pragma unroll
            for (int m = 0; m < j; ++m) s -= M[j][m] * M[j][m];
            float ljj = sqrtf(s);
            M[j][j] = ljj;
            float inv = 1.0f / ljj;
            #pragma unroll
            for (int i2 = j + 1; i2 < 7; ++i2) {
                float s2 = M[i2][j];
                #pragma unroll
                for (int m = 0; m < j; ++m) s2 -= M[i2][m] * M[j][m];
                M[i2][j] = s2 * inv;
            }
        }
        float z[7];
        #pragma unroll
        for (int i2 = 0; i2 < 7; ++i2) {
            float s = rhs[i2];
            #pragma unroll
            for (int m = 0; m < i2; ++m) s -= M[i2][m] * z[m];
            z[i2] = s / M[i2][i2];
        }
        #pragma unroll
        for (int i2 = 6; i2 >= 0; --i2) {
            float s = z[i2];
            #pragma unroll
            for (int m = i2 + 1; m < 7; ++m) s -= M[m][i2] * w[m];
            w[i2] = s / M[i2][i2];
        }

        // stage the 12-float repeating coeff pattern: pat[m] = w[1 + m%6]
        if (lane == 0) {
            float* p = reinterpret_cast<float*>(spat[wave]);
            #pragma unroll
            for (int m = 0; m < 12; ++m) p[m] = w[1 + (m % 6)];
        }
    }
    __syncthreads();

    if (!live) return;

    // ---- coeffs: row = 600 repeats of w[1..6], first 6 timesteps zeroed ----
    {
        float4* crow = reinterpret_cast<float4*>(coeffs + (size_t)row * (SEQ * PP));
        const float4* pw = spat[wave];
        int r = lane % 3;                       // (4*i) % 6 == 4*(i%3) % 6 pattern idx
        for (int i = lane; i < (SEQ * PP) / 4; i += 64) {
            float4 v = pw[r];
            if (i < 9) {                        // flat idx 4i+j < 36  <=>  t < 6
                float* vp = reinterpret_cast<float*>(&v);
                #pragma unroll
                for (int j = 0; j < 4; ++j)
                    if (4 * i + j < PP * PP) vp[j] = 0.f;
            }
            crow[i] = v;
            r = (r == 2) ? 0 : (r + 1);
        }
    }

    // ---- x_hat: 0 for t<6, else AR prediction ----
    {
        float* xh = x_hat + (size_t)row * SEQ;
        for (int e = lane; e < SEQ; e += 64) {
            float v = 0.f;
            if (e >= PP) {
                v = w[0];
                #pragma unroll
                for (int k = 1; k <= 6; ++k) v += w[k] * sx[e - k];
            }
            xh[e] = v;
        }
    }
}

extern "C" void kernel_launch(void* const* d_in, const int* in_sizes, int n_in,
                              void* d_out, int out_size, void* d_ws, size_t ws_size,
                              hipStream_t stream) {
    const float* x = (const float*)d_in[0];
    const int N = in_sizes[0] / SEQ;           // 32768

    float* out    = (float*)d_out;
    float* coeffs = out;                                        // N*600*6
    float* extra  = out + (size_t)N * SEQ * PP;                 // p_logits (N*5) + p_hard (N)
    float* x_hat  = extra + (size_t)N * 6;                      // N*600

    // p_logits and p_hard are all zeros (0 bit pattern valid for f32 and i32)
    hipMemsetAsync(extra, 0, (size_t)N * 6 * sizeof(float), stream);

    dim3 grid((N + 3) / 4), block(256);
    ar_fit_kernel<<<grid, block, 0, stream>>>(x, coeffs, x_hat, N);
}